// Round 7
// baseline (756.419 us; speedup 1.0000x reference)
//
#include <hip/hip_runtime.h>

typedef float f32x4  __attribute__((ext_vector_type(4)));
typedef float f32x16 __attribute__((ext_vector_type(16)));
typedef short s16x8  __attribute__((ext_vector_type(8)));
typedef unsigned int u32;
typedef unsigned int u32x4 __attribute__((ext_vector_type(4)));
typedef unsigned short u16;

#define LL 2048
#define DD 64
#define NITER 32
#define SC_OFF 4194304ull

struct SMem {
    u16   Khi[2][64][72];   // double-buffered K tile [key][d], bf16, stride 144B
    u16   VT [2][64][72];   // double-buffered V^T tile [d][key], bf16
    float bias[2][64];      // double-buffered -1e9*mask per key
};

__device__ __forceinline__ u32 cvt_pk_bf16(float lo, float hi) {
    u32 r;
    asm("v_cvt_pk_bf16_f32 %0, %1, %2" : "=v"(r) : "v"(lo), "v"(hi));
    return r;
}

__global__ __launch_bounds__(512, 4)
void psam_kernel(const float* __restrict__ Qg0, const float* __restrict__ Kg0,
                 const float* __restrict__ Vg0, const int* __restrict__ Mg0,
                 float* __restrict__ out)
{
    __shared__ SMem sm;
    const int tid = threadIdx.x;
    const int w = tid >> 6, l = tid & 63;
    const int j31 = l & 31, h = l >> 5;   // lane col within 32, half-wave
    const int cw = w & 1, iw = w >> 1;    // key-half, query chunk of 32

    // XCD-aware swizzle: all 16 blocks of a (b,h) share one XCD's L2
    const int bid = ((int)blockIdx.x & 7) * 64 + ((int)blockIdx.x >> 3);
    const int bh = bid >> 4;
    const int m0 = (bid & 15) << 7;       // q-row tile start
    const int bB = bh >> 4;               // batch index (H=16)

    const float* Kg = Kg0 + (size_t)bh * LL * DD;
    const float* Vg = Vg0 + (size_t)bh * LL * DD;
    const int*   Mg = Mg0 + (size_t)bB * LL;
    float* So = out + SC_OFF + (size_t)bh * LL * LL + (size_t)m0 * LL;
    float* Oo = out + ((size_t)bh * LL + m0) * DD;

    // ---------- Q fragments (B-operand), single bf16 rounding, direct load ----------
    s16x8 qf[4];
    {
        const float* qr = Qg0 + ((size_t)bh * LL + m0 + iw * 32 + j31) * DD + h * 8;
#pragma unroll
        for (int ks = 0; ks < 4; ++ks) {
            f32x4 a = *(const f32x4*)(qr + ks * 16);
            f32x4 b = *(const f32x4*)(qr + ks * 16 + 4);
            u32x4 qp;
            qp[0] = cvt_pk_bf16(a[0], a[1]);
            qp[1] = cvt_pk_bf16(a[2], a[3]);
            qp[2] = cvt_pk_bf16(b[0], b[1]);
            qp[3] = cvt_pk_bf16(b[2], b[3]);
            qf[ks] = __builtin_bit_cast(s16x8, qp);
        }
    }

    // ---------- tile-0 staging + tile-1 register prefetch ----------
    const int kc = tid >> 3, kd = (tid & 7) * 8;     // K staging: row, col base
    const int vc = tid & 63, vd = (tid >> 6) * 8;    // V staging: key col, d base
    f32x4 kvx, kvy, vvx, vvy;
    int mreg = 0;
    {
        const f32x4* s = (const f32x4*)(Kg + (size_t)kc * DD + kd);
        f32x4 x = s[0], y = s[1];
        u32x4 kp;
        kp[0] = cvt_pk_bf16(x[0], x[1]);
        kp[1] = cvt_pk_bf16(x[2], x[3]);
        kp[2] = cvt_pk_bf16(y[0], y[1]);
        kp[3] = cvt_pk_bf16(y[2], y[3]);
        *(u32x4*)&sm.Khi[0][kc][kd] = kp;
        const f32x4* s2 = (const f32x4*)(Vg + (size_t)vc * DD + vd);
        f32x4 vx = s2[0], vy = s2[1];
#pragma unroll
        for (int i = 0; i < 2; ++i) {
            u32 a0 = cvt_pk_bf16(vx[2 * i], vx[2 * i + 1]);
            sm.VT[0][vd + 2 * i][vc]     = (u16)a0;
            sm.VT[0][vd + 2 * i + 1][vc] = (u16)(a0 >> 16);
            u32 a1 = cvt_pk_bf16(vy[2 * i], vy[2 * i + 1]);
            sm.VT[0][vd + 4 + 2 * i][vc]     = (u16)a1;
            sm.VT[0][vd + 4 + 2 * i + 1][vc] = (u16)(a1 >> 16);
        }
    }
    if (tid < 64) sm.bias[0][tid] = -1.0e9f * (float)Mg[tid];
    {
        const f32x4* s = (const f32x4*)(Kg + (size_t)(64 + kc) * DD + kd);
        kvx = s[0]; kvy = s[1];
        const f32x4* s2 = (const f32x4*)(Vg + (size_t)(64 + vc) * DD + vd);
        vvx = s2[0]; vvy = s2[1];
        if (tid < 64) mreg = Mg[64 + tid];
    }

    f32x16 accO0, accO1;   // OUT partials: own q-chunk x d(0..31 / 32..63), own key-half
#pragma unroll
    for (int e = 0; e < 16; ++e) { accO0[e] = 0.0f; accO1[e] = 0.0f; }

    asm volatile("s_waitcnt lgkmcnt(0)" ::: "memory");
    __builtin_amdgcn_s_barrier();

    int buf = 0;
    for (int t = 0; t < NITER; ++t) {
        const int j0 = t * 64;

        // ---- S = Q*K^T via mfma(A=K, B=Q): col=query, row=key ----
        f32x16 accS;
#pragma unroll
        for (int e = 0; e < 16; ++e) accS[e] = 0.0f;
#pragma unroll
        for (int ks = 0; ks < 4; ++ks) {
            s16x8 kf = *(const s16x8*)&sm.Khi[buf][cw * 32 + j31][ks * 16 + h * 8];
            accS = __builtin_amdgcn_mfma_f32_32x32x16_bf16(kf, qf[ks], accS, 0, 0, 0);
        }

        // ---- softplus + f32x4 NT stores + in-register P pack ----
        u32 wv[4][2];
        float* sp = So + (size_t)(iw * 32 + j31) * LL + j0 + cw * 32 + 4 * h;
#pragma unroll
        for (int g = 0; g < 4; ++g) {
            f32x4 b4 = *(const f32x4*)&sm.bias[buf][cw * 32 + 8 * g + 4 * h];
            f32x4 p;
#pragma unroll
            for (int r = 0; r < 4; ++r) {
                float x  = accS[g * 4 + r] * 0.125f + b4[r];           // qk/8 + mask*(-1e9)
                float tt = __builtin_amdgcn_exp2f(x * 1.44269504f);    // e^x
                p[r] = __builtin_amdgcn_logf(1.0f + tt) * 3.38450771757785852e-4f; // ln(1+e^x)/2048
            }
            __builtin_nontemporal_store(p, (f32x4*)(sp + 8 * g));      // 4 consecutive keys, one q-row
            wv[g][0] = cvt_pk_bf16(p[0], p[1]);                        // keys 8g+4h+{0,1}
            wv[g][1] = cvt_pk_bf16(p[2], p[3]);                        // keys 8g+4h+{2,3}
        }
        // partner (lane ^ 32) copies of all 8 words — guaranteed semantics
        u32 pw[4][2];
#pragma unroll
        for (int g = 0; g < 4; ++g)
#pragma unroll
            for (int j = 0; j < 2; ++j)
                pw[g][j] = (u32)__shfl_xor((int)wv[g][j], 32, 64);

        // ---- OUT += P * V : A-frags assembled in-register, B from VT ----
#pragma unroll
        for (int ks2 = 0; ks2 < 2; ++ks2) {
            u32x4 f;
            f[0] = h ? pw[2 * ks2 + 1][0] : wv[2 * ks2][0];
            f[1] = h ? pw[2 * ks2 + 1][1] : wv[2 * ks2][1];
            f[2] = h ? wv[2 * ks2 + 1][0] : pw[2 * ks2][0];
            f[3] = h ? wv[2 * ks2 + 1][1] : pw[2 * ks2][1];
            s16x8 pa = __builtin_bit_cast(s16x8, f);
            s16x8 vb0 = *(const s16x8*)&sm.VT[buf][j31][cw * 32 + ks2 * 16 + h * 8];
            accO0 = __builtin_amdgcn_mfma_f32_32x32x16_bf16(pa, vb0, accO0, 0, 0, 0);
            s16x8 vb1 = *(const s16x8*)&sm.VT[buf][32 + j31][cw * 32 + ks2 * 16 + h * 8];
            accO1 = __builtin_amdgcn_mfma_f32_32x32x16_bf16(pa, vb1, accO1, 0, 0, 0);
        }

        // ---- staging writes t+1 (regs -> other buffer) ----
        if (t + 1 < NITER) {
            u32x4 kp;
            kp[0] = cvt_pk_bf16(kvx[0], kvx[1]);
            kp[1] = cvt_pk_bf16(kvx[2], kvx[3]);
            kp[2] = cvt_pk_bf16(kvy[0], kvy[1]);
            kp[3] = cvt_pk_bf16(kvy[2], kvy[3]);
            *(u32x4*)&sm.Khi[buf ^ 1][kc][kd] = kp;
#pragma unroll
            for (int i = 0; i < 2; ++i) {
                u32 a0 = cvt_pk_bf16(vvx[2 * i], vvx[2 * i + 1]);
                sm.VT[buf ^ 1][vd + 2 * i][vc]     = (u16)a0;
                sm.VT[buf ^ 1][vd + 2 * i + 1][vc] = (u16)(a0 >> 16);
                u32 a1 = cvt_pk_bf16(vvy[2 * i], vvy[2 * i + 1]);
                sm.VT[buf ^ 1][vd + 4 + 2 * i][vc]     = (u16)a1;
                sm.VT[buf ^ 1][vd + 4 + 2 * i + 1][vc] = (u16)(a1 >> 16);
            }
            if (tid < 64) sm.bias[buf ^ 1][tid] = -1.0e9f * (float)mreg;
        }
        // ---- prefetch tile t+2 into registers ----
        {
            const int tp = (t + 2 < NITER) ? (t + 2) : (NITER - 1);
            const f32x4* s1 = (const f32x4*)(Kg + (size_t)(tp * 64 + kc) * DD + kd);
            kvx = s1[0]; kvy = s1[1];
            const f32x4* s2 = (const f32x4*)(Vg + (size_t)(tp * 64 + vc) * DD + vd);
            vvx = s2[0]; vvy = s2[1];
            if (tid < 64) mreg = Mg[tp * 64 + tid];
        }
        asm volatile("s_waitcnt lgkmcnt(0)" ::: "memory");  // LDS visible; NT stores stay in flight
        __builtin_amdgcn_s_barrier();
        buf ^= 1;
    }

    // ---- epilogue: reduce the two key-half partials, store OUT ----
    float* red = (float*)&sm;   // scratch aliasing staging buffers (all waves past final barrier)
    if (cw == 1) {
#pragma unroll
        for (int dh = 0; dh < 2; ++dh) {
            const f32x16& a = dh ? accO1 : accO0;
#pragma unroll
            for (int e = 0; e < 16; ++e) {
                const int qloc = (e & 3) + 8 * (e >> 2) + 4 * h;
                red[iw * 2048 + qloc * 64 + dh * 32 + j31] = a[e];
            }
        }
    }
    asm volatile("s_waitcnt lgkmcnt(0)" ::: "memory");
    __builtin_amdgcn_s_barrier();
    if (cw == 0) {
#pragma unroll
        for (int dh = 0; dh < 2; ++dh) {
            const f32x16& a = dh ? accO1 : accO0;
#pragma unroll
            for (int e = 0; e < 16; ++e) {
                const int qloc = (e & 3) + 8 * (e >> 2) + 4 * h;
                Oo[(size_t)(iw * 32 + qloc) * DD + dh * 32 + j31] =
                    a[e] + red[iw * 2048 + qloc * 64 + dh * 32 + j31];
            }
        }
    }
}

extern "C" void kernel_launch(void* const* d_in, const int* in_sizes, int n_in,
                              void* d_out, int out_size, void* d_ws, size_t ws_size,
                              hipStream_t stream) {
    const float* q    = (const float*)d_in[0];
    const float* k    = (const float*)d_in[1];
    const float* v    = (const float*)d_in[2];
    const int*   mask = (const int*)d_in[5];   // p_q, p_k unused by reference
    float* out = (float*)d_out;
    hipLaunchKernelGGL(psam_kernel, dim3(512), dim3(512), 0, stream, q, k, v, mask, out);
}

// Round 8
// 122.268 us; speedup vs baseline: 6.1866x; 6.1866x over previous
//
#include <hip/hip_runtime.h>

typedef float f32x4  __attribute__((ext_vector_type(4)));
typedef float f32x16 __attribute__((ext_vector_type(16)));
typedef short s16x8  __attribute__((ext_vector_type(8)));
typedef unsigned int u32;
typedef unsigned int u32x4 __attribute__((ext_vector_type(4)));
typedef unsigned short u16;

#define LL 2048
#define DD 64
#define NITER 32
#define SC_OFF 4194304ull

struct SMem {
    u16 Khi[2][64][72];      // double-buffered K tile [key][d], bf16, 144B stride
    u16 VT [2][64][72];      // double-buffered V^T tile [d][key], bf16
    unsigned char P[4][4096];// per-iw P tile [q 0..31][128B keys], XOR-swizzled rows
};

__device__ __forceinline__ u32 cvt_pk_bf16(float lo, float hi) {
    u32 r;
    asm("v_cvt_pk_bf16_f32 %0, %1, %2" : "=v"(r) : "v"(lo), "v"(hi));
    return r;
}

__global__ __launch_bounds__(512, 4)
void psam_kernel(const float* __restrict__ Qg0, const float* __restrict__ Kg0,
                 const float* __restrict__ Vg0, const int* __restrict__ Mg0,
                 float* __restrict__ out)
{
    __shared__ SMem sm;
    const int tid = threadIdx.x;
    const int w = tid >> 6, l = tid & 63;
    const int j31 = l & 31, h = l >> 5;   // lane index within 32, half-wave
    const int cw = w & 1, iw = w >> 1;    // key-half (QK) / d-half (PV), query chunk
    const int cwj = cw * 32 + j31;        // this lane's key within the 64-key tile

    // XCD-aware swizzle: all 16 blocks of a (b,h) land on one XCD's L2
    const int bid = ((int)blockIdx.x & 7) * 64 + ((int)blockIdx.x >> 3);
    const int bh = bid >> 4;
    const int m0 = (bid & 15) << 7;       // q-row tile start
    const int bB = bh >> 4;               // batch index (H=16)

    const float* Kg = Kg0 + (size_t)bh * LL * DD;
    const float* Vg = Vg0 + (size_t)bh * LL * DD;
    const int*   Mg = Mg0 + (size_t)bB * LL;
    float* So = out + SC_OFF + (size_t)bh * LL * LL + (size_t)m0 * LL;
    float* Oo = out + ((size_t)bh * LL + m0) * DD;

    // ---------- Q fragments (A-operand), single bf16 rounding, direct load ----------
    s16x8 qf[4];
    {
        const float* qr = Qg0 + ((size_t)bh * LL + m0 + iw * 32 + j31) * DD + h * 8;
#pragma unroll
        for (int ks = 0; ks < 4; ++ks) {
            f32x4 a = *(const f32x4*)(qr + ks * 16);
            f32x4 b = *(const f32x4*)(qr + ks * 16 + 4);
            u32x4 qp;
            qp[0] = cvt_pk_bf16(a[0], a[1]);
            qp[1] = cvt_pk_bf16(a[2], a[3]);
            qp[2] = cvt_pk_bf16(b[0], b[1]);
            qp[3] = cvt_pk_bf16(b[2], b[3]);
            qf[ks] = __builtin_bit_cast(s16x8, qp);
        }
    }

    // ---------- tile-0 staging + tile-1 register prefetch ----------
    const int kc = tid >> 3, kd = (tid & 7) * 8;     // K staging: row, col base
    const int vc = tid & 63, vd = (tid >> 6) * 8;    // V staging: key col, d base
    f32x4 kvx, kvy, vvx, vvy;
    {
        const f32x4* s = (const f32x4*)(Kg + (size_t)kc * DD + kd);
        f32x4 x = s[0], y = s[1];
        u32x4 kp;
        kp[0] = cvt_pk_bf16(x[0], x[1]);
        kp[1] = cvt_pk_bf16(x[2], x[3]);
        kp[2] = cvt_pk_bf16(y[0], y[1]);
        kp[3] = cvt_pk_bf16(y[2], y[3]);
        *(u32x4*)&sm.Khi[0][kc][kd] = kp;
        const f32x4* s2 = (const f32x4*)(Vg + (size_t)vc * DD + vd);
        f32x4 vx = s2[0], vy = s2[1];
#pragma unroll
        for (int i = 0; i < 2; ++i) {
            u32 a0 = cvt_pk_bf16(vx[2 * i], vx[2 * i + 1]);
            sm.VT[0][vd + 2 * i][vc]     = (u16)a0;
            sm.VT[0][vd + 2 * i + 1][vc] = (u16)(a0 >> 16);
            u32 a1 = cvt_pk_bf16(vy[2 * i], vy[2 * i + 1]);
            sm.VT[0][vd + 4 + 2 * i][vc]     = (u16)a1;
            sm.VT[0][vd + 4 + 2 * i + 1][vc] = (u16)(a1 >> 16);
        }
    }
    {
        const f32x4* s = (const f32x4*)(Kg + (size_t)(64 + kc) * DD + kd);
        kvx = s[0]; kvy = s[1];
        const f32x4* s2 = (const f32x4*)(Vg + (size_t)(64 + vc) * DD + vd);
        vvx = s2[0]; vvy = s2[1];
    }
    float blc = -1.0e9f * (float)Mg[cwj];
    float bln = -1.0e9f * (float)Mg[64 + cwj];

    f32x16 accO;   // OUT^T: d-half cw x own 32 queries, all keys
#pragma unroll
    for (int e = 0; e < 16; ++e) accO[e] = 0.0f;

    unsigned char* spw = &sm.P[iw][0];
    asm volatile("s_waitcnt lgkmcnt(0)" ::: "memory");
    __builtin_amdgcn_s_barrier();

    f32x16 pA;                 // even-tile softplus results, stores deferred
#pragma unroll
    for (int e = 0; e < 16; ++e) pA[e] = 0.0f;
    float* spA = So;           // even-tile store base

    int buf = 0;
    for (int t = 0; t < NITER; ++t) {
        // ---- S = Q * K^T  (A=Q frags, B=K frags -> col=lane=key) ----
        f32x16 accS;
#pragma unroll
        for (int e = 0; e < 16; ++e) accS[e] = 0.0f;
#pragma unroll
        for (int ks = 0; ks < 4; ++ks) {
            s16x8 kf = *(const s16x8*)&sm.Khi[buf][cwj][ks * 16 + h * 8];
            accS = __builtin_amdgcn_mfma_f32_32x32x16_bf16(qf[ks], kf, accS, 0, 0, 0);
        }
        // C/D layout: col(key)=lane&31, row(query)=r + 8g + 4h
        const float bl = blc;
        float* sp = So + (size_t)(iw * 32 + 4 * h) * LL + t * 64 + cwj;
        f32x16 pc;
#pragma unroll
        for (int g = 0; g < 4; ++g) {
#pragma unroll
            for (int r = 0; r < 4; ++r) {
                float x  = accS[g * 4 + r] * 0.125f + bl;              // qk/8 + mask*(-1e9)
                float tt = __builtin_amdgcn_exp2f(x * 1.44269504f);    // e^x
                float p  = __builtin_amdgcn_logf(1.0f + tt) * 3.38450771757785852e-4f; // ln(1+e^x)/2048
                pc[g * 4 + r] = p;
                const int il = 8 * g + 4 * h + r;                      // local query row
                *(u16*)(spw + ((il * 128 + cwj * 2) ^ ((il & 7) << 4))) = (u16)cvt_pk_bf16(p, p);
            }
        }
        if ((t & 1) == 0) {
            pA = pc; spA = sp;          // defer even-tile stores
        } else {
            // paired stores: per scores row, 256B (tile A) + 256B (tile B) back-to-back
#pragma unroll
            for (int g = 0; g < 4; ++g)
#pragma unroll
                for (int r = 0; r < 4; ++r) {
                    float* ra = spA + (size_t)(8 * g + r) * LL;
                    __builtin_nontemporal_store(pA[g * 4 + r], ra);
                    __builtin_nontemporal_store(pc[g * 4 + r], ra + 64);
                }
        }
        asm volatile("s_waitcnt lgkmcnt(0)" ::: "memory");  // P writes visible; NT stores stay in flight
        __builtin_amdgcn_s_barrier();

        // ---- OUT^T += V^T * P^T  (wave: d-half cw, query chunk iw) ----
#pragma unroll
        for (int ks = 0; ks < 4; ++ks) {
            s16x8 va = *(const s16x8*)&sm.VT[buf][cwj][ks * 16 + h * 8];
            s16x8 pb = *(const s16x8*)(spw + ((j31 * 128 + ks * 32 + h * 16) ^ ((j31 & 7) << 4)));
            accO = __builtin_amdgcn_mfma_f32_32x32x16_bf16(va, pb, accO, 0, 0, 0);
        }

        // ---- staging writes t+1 (regs -> other buffer) ----
        if (t + 1 < NITER) {
            u32x4 kp;
            kp[0] = cvt_pk_bf16(kvx[0], kvx[1]);
            kp[1] = cvt_pk_bf16(kvx[2], kvx[3]);
            kp[2] = cvt_pk_bf16(kvy[0], kvy[1]);
            kp[3] = cvt_pk_bf16(kvy[2], kvy[3]);
            *(u32x4*)&sm.Khi[buf ^ 1][kc][kd] = kp;
#pragma unroll
            for (int i = 0; i < 2; ++i) {
                u32 a0 = cvt_pk_bf16(vvx[2 * i], vvx[2 * i + 1]);
                sm.VT[buf ^ 1][vd + 2 * i][vc]     = (u16)a0;
                sm.VT[buf ^ 1][vd + 2 * i + 1][vc] = (u16)(a0 >> 16);
                u32 a1 = cvt_pk_bf16(vvy[2 * i], vvy[2 * i + 1]);
                sm.VT[buf ^ 1][vd + 4 + 2 * i][vc]     = (u16)a1;
                sm.VT[buf ^ 1][vd + 4 + 2 * i + 1][vc] = (u16)(a1 >> 16);
            }
        }
        // ---- prefetch tile t+2 into registers ----
        {
            const int tp = (t + 2 < NITER) ? (t + 2) : (NITER - 1);
            const f32x4* s1 = (const f32x4*)(Kg + (size_t)(tp * 64 + kc) * DD + kd);
            kvx = s1[0]; kvy = s1[1];
            const f32x4* s2 = (const f32x4*)(Vg + (size_t)(tp * 64 + vc) * DD + vd);
            vvx = s2[0]; vvy = s2[1];
            blc = bln;
            bln = -1.0e9f * (float)Mg[tp * 64 + cwj];
        }
        asm volatile("s_waitcnt lgkmcnt(0)" ::: "memory");  // staging visible; no vmcnt drain
        __builtin_amdgcn_s_barrier();
        buf ^= 1;
    }

    // ---- epilogue: store OUT (col=query j31, row=d = cw*32 + 4h + 8g + r) ----
#pragma unroll
    for (int g = 0; g < 4; ++g) {
        f32x4 o;
#pragma unroll
        for (int r = 0; r < 4; ++r) o[r] = accO[g * 4 + r];
        *(f32x4*)(Oo + (size_t)(iw * 32 + j31) * DD + cw * 32 + h * 4 + g * 8) = o;
    }
}

extern "C" void kernel_launch(void* const* d_in, const int* in_sizes, int n_in,
                              void* d_out, int out_size, void* d_ws, size_t ws_size,
                              hipStream_t stream) {
    const float* q    = (const float*)d_in[0];
    const float* k    = (const float*)d_in[1];
    const float* v    = (const float*)d_in[2];
    const int*   mask = (const int*)d_in[5];   // p_q, p_k unused by reference
    float* out = (float*)d_out;
    hipLaunchKernelGGL(psam_kernel, dim3(512), dim3(512), 0, stream, q, k, v, mask, out);
}

// Round 10
// 121.410 us; speedup vs baseline: 6.2303x; 1.0071x over previous
//
#include <hip/hip_runtime.h>

typedef float f32x4  __attribute__((ext_vector_type(4)));
typedef float f32x16 __attribute__((ext_vector_type(16)));
typedef short s16x8  __attribute__((ext_vector_type(8)));
typedef unsigned int u32;
typedef unsigned int u32x4 __attribute__((ext_vector_type(4)));
typedef unsigned short u16;

#define LL 2048
#define DD 64
#define NITER 32
#define SC_OFF 4194304ull

struct SMem {
    u16 Khi[2][64][72];   // double-buffered K tile [key][d], bf16, 144B stride
    u16 VT [2][64][72];   // double-buffered V^T tile [d][key], bf16
    u16 P[8][32][40];     // wave-private P [q][k own 32 keys], 80B row stride
};

__device__ __forceinline__ u32 cvt_pk_bf16(float lo, float hi) {
    u32 r;
    asm("v_cvt_pk_bf16_f32 %0, %1, %2" : "=v"(r) : "v"(lo), "v"(hi));
    return r;
}

__global__ __launch_bounds__(512, 4)
void psam_kernel(const float* __restrict__ Qg0, const float* __restrict__ Kg0,
                 const float* __restrict__ Vg0, const int* __restrict__ Mg0,
                 float* __restrict__ out)
{
    __shared__ SMem sm;
    const int tid = threadIdx.x;
    const int w = tid >> 6, l = tid & 63;
    const int j31 = l & 31, h = l >> 5;   // lane index within 32, half-wave
    const int cw = w & 1, iw = w >> 1;    // key-half, query chunk of 32
    const int cwj = cw * 32 + j31;        // this lane's key within the 64-key tile

    // XCD-aware swizzle: all 16 blocks of a (b,h) land on one XCD's L2
    const int bid = ((int)blockIdx.x & 7) * 64 + ((int)blockIdx.x >> 3);
    const int bh = bid >> 4;
    const int m0 = (bid & 15) << 7;       // q-row tile start
    const int bB = bh >> 4;               // batch index (H=16)

    const float* Kg = Kg0 + (size_t)bh * LL * DD;
    const float* Vg = Vg0 + (size_t)bh * LL * DD;
    const int*   Mg = Mg0 + (size_t)bB * LL;
    float* So = out + SC_OFF + (size_t)bh * LL * LL + (size_t)m0 * LL;
    float* Oo = out + ((size_t)bh * LL + m0) * DD;

    // ---------- Q fragments (A-operand), single bf16 rounding, direct load ----------
    s16x8 qf[4];
    {
        const float* qr = Qg0 + ((size_t)bh * LL + m0 + iw * 32 + j31) * DD + h * 8;
#pragma unroll
        for (int ks = 0; ks < 4; ++ks) {
            f32x4 a = *(const f32x4*)(qr + ks * 16);
            f32x4 b = *(const f32x4*)(qr + ks * 16 + 4);
            u32x4 qp;
            qp[0] = cvt_pk_bf16(a[0], a[1]);
            qp[1] = cvt_pk_bf16(a[2], a[3]);
            qp[2] = cvt_pk_bf16(b[0], b[1]);
            qp[3] = cvt_pk_bf16(b[2], b[3]);
            qf[ks] = __builtin_bit_cast(s16x8, qp);
        }
    }

    // ---------- tile-0 staging + tile-1 register prefetch ----------
    const int kc = tid >> 3, kd = (tid & 7) * 8;     // K staging: row, col base
    const int vc = tid & 63, vd = (tid >> 6) * 8;    // V staging: key col, d base
    f32x4 kvx, kvy, vvx, vvy;
    {
        const f32x4* s = (const f32x4*)(Kg + (size_t)kc * DD + kd);
        f32x4 x = s[0], y = s[1];
        u32x4 kp;
        kp[0] = cvt_pk_bf16(x[0], x[1]);
        kp[1] = cvt_pk_bf16(x[2], x[3]);
        kp[2] = cvt_pk_bf16(y[0], y[1]);
        kp[3] = cvt_pk_bf16(y[2], y[3]);
        *(u32x4*)&sm.Khi[0][kc][kd] = kp;
        const f32x4* s2 = (const f32x4*)(Vg + (size_t)vc * DD + vd);
        f32x4 vx = s2[0], vy = s2[1];
#pragma unroll
        for (int i = 0; i < 2; ++i) {
            u32 a0 = cvt_pk_bf16(vx[2 * i], vx[2 * i + 1]);
            sm.VT[0][vd + 2 * i][vc]     = (u16)a0;
            sm.VT[0][vd + 2 * i + 1][vc] = (u16)(a0 >> 16);
            u32 a1 = cvt_pk_bf16(vy[2 * i], vy[2 * i + 1]);
            sm.VT[0][vd + 4 + 2 * i][vc]     = (u16)a1;
            sm.VT[0][vd + 4 + 2 * i + 1][vc] = (u16)(a1 >> 16);
        }
    }
    {
        const f32x4* s = (const f32x4*)(Kg + (size_t)(64 + kc) * DD + kd);
        kvx = s[0]; kvy = s[1];
        const f32x4* s2 = (const f32x4*)(Vg + (size_t)(64 + vc) * DD + vd);
        vvx = s2[0]; vvy = s2[1];
    }
    float blc = -1.0e9f * (float)Mg[cwj];
    float bln = -1.0e9f * (float)Mg[64 + cwj];

    f32x16 accO0, accO1;   // OUT^T partials: q = iw*32+j31, d = regmap (+32), own keys
#pragma unroll
    for (int e = 0; e < 16; ++e) { accO0[e] = 0.0f; accO1[e] = 0.0f; }

    u16* spw = &sm.P[w][0][0];
    asm volatile("s_waitcnt lgkmcnt(0)" ::: "memory");
    __builtin_amdgcn_s_barrier();

    f32x16 pA;                 // even-tile softplus results, stores deferred
#pragma unroll
    for (int e = 0; e < 16; ++e) pA[e] = 0.0f;
    float* spA = So;

    int buf = 0;
    for (int t = 0; t < NITER; ++t) {
        // ---- S = Q * K^T  (A=Q frags, B=K frags -> col=lane=key) ----
        f32x16 accS;
#pragma unroll
        for (int e = 0; e < 16; ++e) accS[e] = 0.0f;
#pragma unroll
        for (int ks = 0; ks < 4; ++ks) {
            s16x8 kf = *(const s16x8*)&sm.Khi[buf][cwj][ks * 16 + h * 8];
            accS = __builtin_amdgcn_mfma_f32_32x32x16_bf16(qf[ks], kf, accS, 0, 0, 0);
        }
        // C/D layout: col(key)=lane&31, row(query)=r + 8g + 4h
        const float bl = blc;
        float* sp = So + (size_t)(iw * 32 + 4 * h) * LL + t * 64 + cwj;
        f32x16 pc;
#pragma unroll
        for (int g = 0; g < 4; ++g) {
#pragma unroll
            for (int r = 0; r < 4; ++r) {
                float x  = accS[g * 4 + r] * 0.125f + bl;              // qk/8 + mask*(-1e9)
                float tt = __builtin_amdgcn_exp2f(x * 1.44269504f);    // e^x
                float p  = __builtin_amdgcn_logf(1.0f + tt) * 3.38450771757785852e-4f; // ln(1+e^x)/2048
                pc[g * 4 + r] = p;
                const int il = 8 * g + 4 * h + r;                      // local query row
                spw[il * 40 + j31] = (u16)cvt_pk_bf16(p, p);           // wave-private P
            }
        }
        if ((t & 1) == 0) {
            pA = pc; spA = sp;          // defer even-tile stores
        } else {
            // paired stores: per scores row, two 256B windows back-to-back
#pragma unroll
            for (int g = 0; g < 4; ++g)
#pragma unroll
                for (int r = 0; r < 4; ++r) {
                    float* ra = spA + (size_t)(8 * g + r) * LL;
                    __builtin_nontemporal_store(pA[g * 4 + r], ra);
                    __builtin_nontemporal_store(pc[g * 4 + r], ra + 64);
                }
        }
        asm volatile("s_waitcnt lgkmcnt(0)" ::: "memory");  // own P writes complete (same-wave)

        // ---- OUT^T += V^T(own keys) * P^T  — wave-private, NO barrier ----
        // element: OUT[q = iw*32 + j31][d = regmap (+32 for accO1)]   (R5-validated)
#pragma unroll
        for (int ks2 = 0; ks2 < 2; ++ks2) {
            s16x8 pb = *(const s16x8*)(spw + j31 * 40 + ks2 * 16 + h * 8);
            s16x8 va0 = *(const s16x8*)&sm.VT[buf][j31][cw * 32 + ks2 * 16 + h * 8];
            accO0 = __builtin_amdgcn_mfma_f32_32x32x16_bf16(va0, pb, accO0, 0, 0, 0);
            s16x8 va1 = *(const s16x8*)&sm.VT[buf][32 + j31][cw * 32 + ks2 * 16 + h * 8];
            accO1 = __builtin_amdgcn_mfma_f32_32x32x16_bf16(va1, pb, accO1, 0, 0, 0);
        }

        // ---- staging writes t+1 (regs -> other buffer) ----
        if (t + 1 < NITER) {
            u32x4 kp;
            kp[0] = cvt_pk_bf16(kvx[0], kvx[1]);
            kp[1] = cvt_pk_bf16(kvx[2], kvx[3]);
            kp[2] = cvt_pk_bf16(kvy[0], kvy[1]);
            kp[3] = cvt_pk_bf16(kvy[2], kvy[3]);
            *(u32x4*)&sm.Khi[buf ^ 1][kc][kd] = kp;
#pragma unroll
            for (int i = 0; i < 2; ++i) {
                u32 a0 = cvt_pk_bf16(vvx[2 * i], vvx[2 * i + 1]);
                sm.VT[buf ^ 1][vd + 2 * i][vc]     = (u16)a0;
                sm.VT[buf ^ 1][vd + 2 * i + 1][vc] = (u16)(a0 >> 16);
                u32 a1 = cvt_pk_bf16(vvy[2 * i], vvy[2 * i + 1]);
                sm.VT[buf ^ 1][vd + 4 + 2 * i][vc]     = (u16)a1;
                sm.VT[buf ^ 1][vd + 4 + 2 * i + 1][vc] = (u16)(a1 >> 16);
            }
        }
        // ---- prefetch tile t+2 into registers ----
        {
            const int tp = (t + 2 < NITER) ? (t + 2) : (NITER - 1);
            const f32x4* s1 = (const f32x4*)(Kg + (size_t)(tp * 64 + kc) * DD + kd);
            kvx = s1[0]; kvy = s1[1];
            const f32x4* s2 = (const f32x4*)(Vg + (size_t)(tp * 64 + vc) * DD + vd);
            vvx = s2[0]; vvy = s2[1];
            blc = bln;
            bln = -1.0e9f * (float)Mg[tp * 64 + cwj];
        }
        asm volatile("s_waitcnt lgkmcnt(0)" ::: "memory");  // staging visible; NT stores in flight
        __builtin_amdgcn_s_barrier();                        // the ONLY barrier per tile
        buf ^= 1;
    }

    // ---- epilogue: R5-validated reduction + store ----
    float* red = (float*)&sm;   // scratch aliasing staging buffers
    if (cw == 1) {
#pragma unroll
        for (int db = 0; db < 2; ++db) {
            const f32x16& a = db ? accO1 : accO0;
#pragma unroll
            for (int g = 0; g < 4; ++g)
#pragma unroll
                for (int r = 0; r < 4; ++r) {
                    const int row = db * 32 + 8 * g + 4 * h + r;   // d within 0..63
                    red[(size_t)(iw * 64 + row) * 32 + j31] = a[g * 4 + r];
                }
        }
    }
    asm volatile("s_waitcnt lgkmcnt(0)" ::: "memory");
    __builtin_amdgcn_s_barrier();
    if (cw == 0) {
        float* op = Oo + (size_t)(iw * 32 + j31) * DD;
#pragma unroll
        for (int db = 0; db < 2; ++db) {
            const f32x16& a = db ? accO1 : accO0;
#pragma unroll
            for (int g = 0; g < 4; ++g) {
                f32x4 o;
#pragma unroll
                for (int r = 0; r < 4; ++r) {
                    const int row = db * 32 + 8 * g + 4 * h + r;
                    o[r] = a[g * 4 + r] + red[(size_t)(iw * 64 + row) * 32 + j31];
                }
                *(f32x4*)(op + db * 32 + 8 * g + 4 * h) = o;
            }
        }
    }
}

extern "C" void kernel_launch(void* const* d_in, const int* in_sizes, int n_in,
                              void* d_out, int out_size, void* d_ws, size_t ws_size,
                              hipStream_t stream) {
    const float* q    = (const float*)d_in[0];
    const float* k    = (const float*)d_in[1];
    const float* v    = (const float*)d_in[2];
    const int*   mask = (const int*)d_in[5];   // p_q, p_k unused by reference
    float* out = (float*)d_out;
    hipLaunchKernelGGL(psam_kernel, dim3(512), dim3(512), 0, stream, q, k, v, mask, out);
}